// Round 11
// baseline (393.926 us; speedup 1.0000x reference)
//
#include <hip/hip_runtime.h>
#include <hip/hip_bf16.h>
#include <math.h>

#define BNROWS (4096*32)   // 131072
#define RB     64          // rows per MLP block
#define LN32   3.4657359027997265f

typedef __attribute__((ext_vector_type(8))) short bf16x8;
typedef __attribute__((ext_vector_type(4))) float f32x4;

static __device__ __forceinline__ ushort f2bf(float x) {
    union { __hip_bfloat16 h; ushort u; } cv;
    cv.h = __float2bfloat16(x);
    return cv.u;
}

// ---------------------------------------------------------------------------
__global__ void obs_to_bf16(const float* __restrict__ obs,
                            ushort* __restrict__ obs_bf) {
    size_t i = ((size_t)blockIdx.x * 256 + threadIdx.x) * 4;
    float4 v = *(const float4*)&obs[i];
    ushort4 o;
    o.x = f2bf(v.x); o.y = f2bf(v.y); o.z = f2bf(v.z); o.w = f2bf(v.w);
    *(ushort4*)&obs_bf[i] = o;
}

// ---------------------------------------------------------------------------
// Pack weights into MFMA fragment order (lane-contiguous 16B loads).
// Lane (q,m): element j -> W[k = c*32 + q*8 + j][n = tile*16 + m].
__global__ void prep_pack(const float* __restrict__ w1,
                          const float* __restrict__ w2,
                          ushort* __restrict__ pB1, ushort* __restrict__ pB2,
                          ushort* __restrict__ pB3, ushort* __restrict__ pB4) {
    int g = blockIdx.x * 256 + threadIdx.x;   // 19968 total
    ushort out[8];
    ushort* dst;
    if (g < 3072) {
        int lane = g & 63, gc = g >> 6;
        int t = gc / 3, c = gc % 3;
        int m = lane & 15, q = lane >> 4, n = t * 16 + m;
        #pragma unroll
        for (int j = 0; j < 8; ++j) {
            int k = c * 32 + q * 8 + j;
            out[j] = f2bf((k < 80) ? w1[k * 256 + n] : 0.f);
        }
        dst = &pB1[g * 8];
    } else if (g < 11264) {
        int gg = g - 3072;
        int lane = gg & 63, gc = gg >> 6;
        int t = gc >> 3, c = gc & 7;
        int m = lane & 15, q = lane >> 4, n = t * 16 + m;
        #pragma unroll
        for (int j = 0; j < 8; ++j)
            out[j] = f2bf(w2[(c * 32 + q * 8 + j) * 256 + n]);
        dst = &pB2[gg * 8];
    } else if (g < 19456) {
        int gg = g - 11264;
        int lane = gg & 63, gc = gg >> 6;
        int t = gc >> 3, c = gc & 7;
        int m = lane & 15, q = lane >> 4;
        #pragma unroll
        for (int j = 0; j < 8; ++j)
            out[j] = f2bf(w2[(t * 16 + m) * 256 + c * 32 + q * 8 + j]);
        dst = &pB3[gg * 8];
    } else if (g < 19968) {
        int gg = g - 19456;
        int lane = gg & 63, c = gg >> 6;
        int m = lane & 15, q = lane >> 4;
        #pragma unroll
        for (int j = 0; j < 8; ++j)
            out[j] = f2bf(w1[(64 + m) * 256 + c * 32 + q * 8 + j]);
        dst = &pB4[gg * 8];
    } else return;
    *(uint4*)dst = *(uint4*)out;
}

// ---------------------------------------------------------------------------
// Fused critic forward + VJP, bf16 MFMA, swapped operands (round-6 layout).
// 512 threads / 8 waves, wave w owns col-tiles {2w, 2w+1} x 4 row-tiles.
// 57 us, VGPR 60, MfmaUtil 28.5% (r10). Structure-bound: 256-thr and 512-thr
// variants measured identical; TLP/width knobs are neutral. Unchanged.
// Plain __launch_bounds__: min-wave bounds spilled (r3/r4/r5).
__global__ __launch_bounds__(512) void mlp_mfma(
    const ushort* __restrict__ obs_bf,  // [BN,64] bf16
    const float* __restrict__ a_in,     // [BN,16]
    const float* __restrict__ b1,       // [256]
    const float* __restrict__ b2,       // [256]
    const float* __restrict__ w3,       // [256]
    const float* __restrict__ b3,       // [1]
    const ushort* __restrict__ pB1, const ushort* __restrict__ pB2,
    const ushort* __restrict__ pB3, const ushort* __restrict__ pB4,
    float* __restrict__ score,          // [BN,16]
    float* __restrict__ qout)           // [BN]
{
    __shared__ __align__(16) ushort B0[RB * 264];   // h1 -> dz2 -> dz1
    __shared__ __align__(16) ushort B1s[RB * 104];  // h0
    __shared__ float qpart[8][RB];
    __shared__ float bias1[256], bias2[256], w3s[256];

    const int tid  = threadIdx.x;
    const int row0 = blockIdx.x * RB;

    // ---- Phase A: stage h0 = [obs_bf16 | a->bf16 | 0pad] at stride 104
    {
        int r = tid >> 3, ch = tid & 7;                    // 512 units exactly
        *(uint4*)&B1s[r * 104 + ch * 8] =
            *(const uint4*)&obs_bf[(size_t)(row0 + r) * 64 + ch * 8];
    }
    if (tid < 256) {
        int r = tid >> 2, d0 = (tid & 3) * 4;
        float4 av = *(const float4*)&a_in[(size_t)(row0 + r) * 16 + d0];
        ushort4 pv;
        pv.x = f2bf(av.x); pv.y = f2bf(av.y); pv.z = f2bf(av.z); pv.w = f2bf(av.w);
        *(ushort4*)&B1s[r * 104 + 64 + d0] = pv;
        ushort4 zv; zv.x = zv.y = zv.z = zv.w = 0;
        *(ushort4*)&B1s[r * 104 + 80 + d0] = zv;
        bias1[tid] = b1[tid]; bias2[tid] = b2[tid]; w3s[tid] = w3[tid];
    }
    __syncthreads();                                       // (1)

    const int lane = tid & 63;
    const int w    = tid >> 6;        // wave 0..7 -> col-tiles {2w, 2w+1}
    const int m    = lane & 15;
    const int q    = lane >> 4;
    const int qk   = q * 8;

    f32x4 acc[4][2];                  // [row-tile][col-tile-in-wave]
    unsigned relumask = 0u;           // 32 bits: rt*8 + tc*4 + i

    // ---- Phase B: z1 = h0 @ w1 (+b1) ; relu -> B0 ; mask -> regs
    #pragma unroll
    for (int tc = 0; tc < 2; ++tc)
        #pragma unroll
        for (int rt = 0; rt < 4; ++rt) acc[rt][tc] = (f32x4){0.f, 0.f, 0.f, 0.f};
    for (int c = 0; c < 3; ++c) {
        bf16x8 af[4];
        #pragma unroll
        for (int rt = 0; rt < 4; ++rt)
            af[rt] = *(const bf16x8*)&B1s[(rt * 16 + m) * 104 + c * 32 + qk];
        #pragma unroll
        for (int tc = 0; tc < 2; ++tc) {
            bf16x8 wfr = *(const bf16x8*)&pB1[(((w * 2 + tc) * 3 + c) * 64 + lane) * 8];
            #pragma unroll
            for (int rt = 0; rt < 4; ++rt)
                acc[rt][tc] = __builtin_amdgcn_mfma_f32_16x16x32_bf16(wfr, af[rt], acc[rt][tc], 0, 0, 0);
        }
    }
    #pragma unroll
    for (int tc = 0; tc < 2; ++tc) {
        const float4 bv = *(const float4*)&bias1[(w * 2 + tc) * 16 + q * 4];
        const float bva[4] = {bv.x, bv.y, bv.z, bv.w};
        #pragma unroll
        for (int rt = 0; rt < 4; ++rt) {
            ushort4 pk;
            float z0 = acc[rt][tc][0] + bva[0];
            float z1 = acc[rt][tc][1] + bva[1];
            float z2 = acc[rt][tc][2] + bva[2];
            float z3 = acc[rt][tc][3] + bva[3];
            if (z0 > 0.f) relumask |= 1u << (rt * 8 + tc * 4 + 0);
            if (z1 > 0.f) relumask |= 1u << (rt * 8 + tc * 4 + 1);
            if (z2 > 0.f) relumask |= 1u << (rt * 8 + tc * 4 + 2);
            if (z3 > 0.f) relumask |= 1u << (rt * 8 + tc * 4 + 3);
            pk.x = f2bf(fmaxf(z0, 0.f)); pk.y = f2bf(fmaxf(z1, 0.f));
            pk.z = f2bf(fmaxf(z2, 0.f)); pk.w = f2bf(fmaxf(z3, 0.f));
            *(ushort4*)&B0[(rt * 16 + m) * 264 + (w * 2 + tc) * 16 + q * 4] = pk;
        }
    }
    __syncthreads();                                       // (2)

    // ---- Phase C: z2 = h1 @ w2 (+b2) ; q partials ; dz2 -> B0
    #pragma unroll
    for (int tc = 0; tc < 2; ++tc)
        #pragma unroll
        for (int rt = 0; rt < 4; ++rt) acc[rt][tc] = (f32x4){0.f, 0.f, 0.f, 0.f};
    for (int c = 0; c < 8; ++c) {
        bf16x8 af[4];
        #pragma unroll
        for (int rt = 0; rt < 4; ++rt)
            af[rt] = *(const bf16x8*)&B0[(rt * 16 + m) * 264 + c * 32 + qk];
        #pragma unroll
        for (int tc = 0; tc < 2; ++tc) {
            bf16x8 wfr = *(const bf16x8*)&pB2[(((w * 2 + tc) * 8 + c) * 64 + lane) * 8];
            #pragma unroll
            for (int rt = 0; rt < 4; ++rt)
                acc[rt][tc] = __builtin_amdgcn_mfma_f32_16x16x32_bf16(wfr, af[rt], acc[rt][tc], 0, 0, 0);
        }
    }
    __syncthreads();                                       // (3)
    {
        float qp[4] = {0.f, 0.f, 0.f, 0.f};
        #pragma unroll
        for (int tc = 0; tc < 2; ++tc) {
            const float4 bv = *(const float4*)&bias2[(w * 2 + tc) * 16 + q * 4];
            const float4 wv = *(const float4*)&w3s[(w * 2 + tc) * 16 + q * 4];
            const float bva[4] = {bv.x, bv.y, bv.z, bv.w};
            const float wva[4] = {wv.x, wv.y, wv.z, wv.w};
            #pragma unroll
            for (int rt = 0; rt < 4; ++rt) {
                ushort4 pk; float dz[4];
                #pragma unroll
                for (int i = 0; i < 4; ++i) {
                    float z = acc[rt][tc][i] + bva[i];
                    if (z > 0.f) { qp[rt] += z * wva[i]; dz[i] = wva[i]; }
                    else         { dz[i] = 0.f; }
                }
                pk.x = f2bf(dz[0]); pk.y = f2bf(dz[1]);
                pk.z = f2bf(dz[2]); pk.w = f2bf(dz[3]);
                *(ushort4*)&B0[(rt * 16 + m) * 264 + (w * 2 + tc) * 16 + q * 4] = pk;
            }
        }
        #pragma unroll
        for (int rt = 0; rt < 4; ++rt) {
            float v = qp[rt];
            v += __shfl_xor(v, 16); v += __shfl_xor(v, 32);
            if (q == 0) qpart[w][rt * 16 + m] = v;
        }
    }
    __syncthreads();                                       // (4)

    if (tid < RB) {
        float qs = b3[0];
        #pragma unroll
        for (int ww = 0; ww < 8; ++ww) qs += qpart[ww][tid];
        qout[row0 + tid] = qs;
    }

    // ---- Phase D: dh1 = dz2 @ w2^T ; dz1 = dh1 * mask -> B0
    #pragma unroll
    for (int tc = 0; tc < 2; ++tc)
        #pragma unroll
        for (int rt = 0; rt < 4; ++rt) acc[rt][tc] = (f32x4){0.f, 0.f, 0.f, 0.f};
    for (int c = 0; c < 8; ++c) {
        bf16x8 af[4];
        #pragma unroll
        for (int rt = 0; rt < 4; ++rt)
            af[rt] = *(const bf16x8*)&B0[(rt * 16 + m) * 264 + c * 32 + qk];
        #pragma unroll
        for (int tc = 0; tc < 2; ++tc) {
            bf16x8 wfr = *(const bf16x8*)&pB3[(((w * 2 + tc) * 8 + c) * 64 + lane) * 8];
            #pragma unroll
            for (int rt = 0; rt < 4; ++rt)
                acc[rt][tc] = __builtin_amdgcn_mfma_f32_16x16x32_bf16(wfr, af[rt], acc[rt][tc], 0, 0, 0);
        }
    }
    __syncthreads();                                       // (5)
    #pragma unroll
    for (int rt = 0; rt < 4; ++rt)
        #pragma unroll
        for (int tc = 0; tc < 2; ++tc) {
            ushort4 pk;
            pk.x = f2bf((relumask >> (rt * 8 + tc * 4 + 0)) & 1u ? acc[rt][tc][0] : 0.f);
            pk.y = f2bf((relumask >> (rt * 8 + tc * 4 + 1)) & 1u ? acc[rt][tc][1] : 0.f);
            pk.z = f2bf((relumask >> (rt * 8 + tc * 4 + 2)) & 1u ? acc[rt][tc][2] : 0.f);
            pk.w = f2bf((relumask >> (rt * 8 + tc * 4 + 3)) & 1u ? acc[rt][tc][3] : 0.f);
            *(ushort4*)&B0[(rt * 16 + m) * 264 + (w * 2 + tc) * 16 + q * 4] = pk;
        }
    __syncthreads();                                       // (6)

    // ---- Phase E: score = dz1 @ w1[64:80]^T (waves 0..3, row-tile w)
    if (w < 4) {
        f32x4 acc2 = (f32x4){0.f, 0.f, 0.f, 0.f};
        for (int c = 0; c < 8; ++c) {
            bf16x8 af = *(const bf16x8*)&B0[(w * 16 + m) * 264 + c * 32 + qk];
            bf16x8 wfr = *(const bf16x8*)&pB4[(c * 64 + lane) * 8];
            acc2 = __builtin_amdgcn_mfma_f32_16x16x32_bf16(wfr, af, acc2, 0, 0, 0);
        }
        float4 o; o.x = acc2[0]; o.y = acc2[1]; o.z = acc2[2]; o.w = acc2[3];
        *(float4*)&score[(size_t)(row0 + w * 16 + m) * 16 + q * 4] = o;
    }
}

// ---------------------------------------------------------------------------
// SVGD v3 (round-10 structure) with round-11 occupancy bump:
// __launch_bounds__(256, 6): 6 waves/EU -> 6 blocks/CU (was 4), VGPR budget 85
// (kernel used 64 at (256,4) — headroom, no spill expected).
// (256,8) forced 32 VGPRs -> 1 GB spill (r3). Tripwire: hbm_bytes >> 60 MB.
__global__ __launch_bounds__(256, 6) void svgd_kernel(
    const float* __restrict__ a_in,    // [BN,16]
    const float* __restrict__ score,   // [BN,16]
    const float* __restrict__ logp_in, // [BN] (ignored if first)
    float* __restrict__ logp_out,      // [BN]
    float* __restrict__ a_out,         // [BN,16]
    int first)
{
    __shared__ float X[32 * 17], S[32 * 17];
    __shared__ float KM[32 * 40];
    __shared__ int hist[2048];
    __shared__ int wsum[4];
    __shared__ int bbin, bexcl;
    __shared__ int redc[4];
    __shared__ unsigned redm[4];

    const int b = blockIdx.x, tid = threadIdx.x;
    const int lane = tid & 63, wv = tid >> 6;
    const size_t base = (size_t)b * 512;

    for (int idx = tid; idx < 512; idx += 256) {
        int r = idx >> 4, d = idx & 15;
        X[r * 17 + d] = a_in[base + idx];
        S[r * 17 + d] = score[base + idx];
    }
    __syncthreads();

    // dist^2 (bits) and P fused; thread owns pairs (i = tid>>5 + 8t, j = tid&31)
    unsigned v[4]; float p[4];
    #pragma unroll
    for (int t = 0; t < 4; ++t) {
        int idx = tid + 256 * t, i = idx >> 5, j = idx & 31;
        float s = 0.f, pp = 0.f;
        #pragma unroll
        for (int d = 0; d < 16; ++d) {
            float df = X[i * 17 + d] - X[j * 17 + d];
            s  = fmaf(df, df, s);
            pp = fmaf(df, S[j * 17 + d], pp);
        }
        v[t] = __float_as_uint(s);
        p[t] = pp;
    }

    // ---- 3-pass radix select: rank-511 value (bit-exact)
    unsigned prefix = 0;
    int rank = 511;
    #pragma unroll
    for (int pass = 0; pass < 3; ++pass) {
        const int sh = (pass == 0) ? 21 : (pass == 1) ? 10 : 0;
        const unsigned dmask = (pass == 2) ? 1023u : 2047u;
        #pragma unroll
        for (int k = 0; k < 8; ++k) hist[tid + 256 * k] = 0;
        __syncthreads();
        #pragma unroll
        for (int t = 0; t < 4; ++t) {
            bool ok = (pass == 0) ||
                      ((v[t] >> (sh + ((pass == 1) ? 11 : 10))) == prefix);
            if (ok) atomicAdd(&hist[(v[t] >> sh) & dmask], 1);
        }
        __syncthreads();
        int c[8], ct = 0;
        #pragma unroll
        for (int k = 0; k < 8; ++k) { c[k] = hist[8 * tid + k]; ct += c[k]; }
        int inc = ct;
        #pragma unroll
        for (int off = 1; off < 64; off <<= 1) {
            int tt = __shfl_up(inc, off, 64);
            if (lane >= off) inc += tt;
        }
        if (lane == 63) wsum[wv] = inc;
        __syncthreads();
        int run = inc - ct;
        for (int ww = 0; ww < wv; ++ww) run += wsum[ww];
        #pragma unroll
        for (int k = 0; k < 8; ++k) {
            if (c[k] > 0 && rank >= run && rank < run + c[k]) {
                bbin = 8 * tid + k; bexcl = run;
            }
            run += c[k];
        }
        __syncthreads();
        prefix = (prefix << ((pass == 2) ? 10 : 11)) | (unsigned)bbin;
        rank -= bexcl;
    }
    const float v1 = __uint_as_float(prefix);

    // rank-512 value: v1 again if count(x<=v1)>=513 else min of x>v1
    float med;
    {
        int cle = 0;
        unsigned mgt = 0xFFFFFFFFu;
        #pragma unroll
        for (int t = 0; t < 4; ++t) {
            if (v[t] <= prefix) cle++;
            else mgt = min(mgt, v[t]);
        }
        #pragma unroll
        for (int off = 1; off < 64; off <<= 1) {
            cle += __shfl_xor(cle, off);
            mgt = min(mgt, (unsigned)__shfl_xor((int)mgt, off));
        }
        if (lane == 0) { redc[wv] = cle; redm[wv] = mgt; }
        __syncthreads();
        int C = redc[0] + redc[1] + redc[2] + redc[3];
        unsigned M = min(min(redm[0], redm[1]), min(redm[2], redm[3]));
        float v2 = (C >= 513) ? v1 : __uint_as_float(M);
        med = 0.5f * (v1 + v2);
    }
    const float gamma = 1.0f / (2.0f * (med / LN32 + 1e-8f));

    // ---- K: registers + LDS (stride 40; write banks (8i+j)&31 distinct)
    float kreg[4];
    #pragma unroll
    for (int t = 0; t < 4; ++t) {
        int idx = tid + 256 * t, i = idx >> 5, j = idx & 31;
        float kk = __expf(-gamma * __uint_as_float(v[t]));
        kreg[t] = kk;
        KM[i * 40 + j] = kk;
    }

    // ---- logp from registers (no LDS, no barrier): butterfly over j=lane&31
    {
        float acc1[4], acc2[4];
        #pragma unroll
        for (int t = 0; t < 4; ++t) {
            float a1 = kreg[t] * p[t];
            float a2 = (2.f * gamma * __uint_as_float(v[t]) - 16.f) * kreg[t];
            #pragma unroll
            for (int off = 1; off < 32; off <<= 1) {
                a1 += __shfl_xor(a1, off);
                a2 += __shfl_xor(a2, off);
            }
            acc1[t] = a1; acc2[t] = a2;
        }
        if ((tid & 31) == 0) {
            #pragma unroll
            for (int t = 0; t < 4; ++t) {
                int i = (tid >> 5) + 8 * t;
                float tmp = -2.f * gamma * (acc1[t] + acc2[t]) * (1.f / 32.f);
                float prev = first ? 0.f : logp_in[b * 32 + i];
                logp_out[b * 32 + i] = prev - 0.1f * tmp;
            }
        }
    }
    __syncthreads();                   // KM visible for phi

    // ---- phi + particle update
    for (int idx = tid; idx < 512; idx += 256) {
        int i = idx >> 4, d = idx & 15;
        float s1 = 0.f, s2 = 0.f;
        float xi = X[i * 17 + d];
        #pragma unroll
        for (int j = 0; j < 32; ++j) {
            float kk = KM[i * 40 + j];
            s1 = fmaf(kk, S[j * 17 + d], s1);
            s2 = fmaf(kk, xi - X[j * 17 + d], s2);
        }
        float phi = (s1 + 2.f * gamma * s2) * (1.f / 32.f);
        float av = xi + 0.1f * phi;
        av = fminf(fmaxf(av, -1.f), 1.f);
        a_out[base + idx] = av;
    }
}

// ---------------------------------------------------------------------------
extern "C" void kernel_launch(void* const* d_in, const int* in_sizes, int n_in,
                              void* d_out, int out_size, void* d_ws, size_t ws_size,
                              hipStream_t stream) {
    const float* obs = (const float*)d_in[0];
    const float* a0  = (const float*)d_in[1];
    const float* w1  = (const float*)d_in[2];
    const float* b1  = (const float*)d_in[3];
    const float* w2  = (const float*)d_in[4];
    const float* b2  = (const float*)d_in[5];
    const float* w3  = (const float*)d_in[6];
    const float* b3  = (const float*)d_in[7];

    float* out_a    = (float*)d_out;                 // [BN,16]
    float* out_logp = out_a + (size_t)BNROWS * 16;   // [BN]
    float* out_q    = out_logp + BNROWS;             // [BN]

    char* p = (char*)d_ws;
    ushort* pB1 = (ushort*)p; p += 24576 * 2;
    ushort* pB2 = (ushort*)p; p += 65536 * 2;
    ushort* pB3 = (ushort*)p; p += 65536 * 2;
    ushort* pB4 = (ushort*)p; p += 4096 * 2;
    ushort* obs_bf = (ushort*)p; p += (size_t)BNROWS * 64 * 2;
    float* abuf0 = (float*)p; p += (size_t)BNROWS * 16 * 4;
    float* abuf1 = (float*)p; p += (size_t)BNROWS * 16 * 4;
    float* scr   = (float*)p; p += (size_t)BNROWS * 16 * 4;
    float* logp  = (float*)p; p += (size_t)BNROWS * 4;
    float* qtmp  = (float*)p;

    prep_pack<<<78, 256, 0, stream>>>(w1, w2, pB1, pB2, pB3, pB4);
    obs_to_bf16<<<8192, 256, 0, stream>>>(obs, obs_bf);

    const int MB = BNROWS / RB;   // 2048 blocks

    // step 1
    mlp_mfma<<<MB, 512, 0, stream>>>(obs_bf, a0, b1, b2, w3, b3,
                                     pB1, pB2, pB3, pB4, scr, qtmp);
    svgd_kernel<<<4096, 256, 0, stream>>>(a0, scr, nullptr, logp, abuf0, 1);
    // step 2
    mlp_mfma<<<MB, 512, 0, stream>>>(obs_bf, abuf0, b1, b2, w3, b3,
                                     pB1, pB2, pB3, pB4, scr, qtmp);
    svgd_kernel<<<4096, 256, 0, stream>>>(abuf0, scr, logp, logp, abuf1, 0);
    // step 3 (q of this step is the q_vals output)
    mlp_mfma<<<MB, 512, 0, stream>>>(obs_bf, abuf1, b1, b2, w3, b3,
                                     pB1, pB2, pB3, pB4, scr, out_q);
    svgd_kernel<<<4096, 256, 0, stream>>>(abuf1, scr, logp, out_logp, out_a, 0);
}